// Round 5
// baseline (51.205 us; speedup 1.0000x reference)
//
#include <hip/hip_runtime.h>

// DiscreteLinear: z[b,i] = sum_j weight[a[b],i,j] * x[b,j] + bias[a[b],i]
// B=2048, A=64, D=512.
// R4: revert to R2 tiling (BN=64, 512 blocks, each wave does 16 cols x 4
// m-chunks). Occupancy lever: SINGLE-buffered LDS (32.3 KB vs 64 KB) ->
// 4 blocks/CU, 16 waves/CU (2x R2). launch_bounds(256,4) gives the
// compiler a 128-VGPR budget so the 16 prefetched float4 loads can
// actually stay in flight (R2/R3 compiled to 48 VGPRs = serialized).
// Keep R3's bucket + skip-staging of x rows >= rem.

#define NA 64
#define DD 512
#define NB 2048
#define BN 64           // output cols per block
#define BK 128          // K chunk
#define NKC (DD / BK)   // 4 chunks

typedef __bf16  bf16x8  __attribute__((ext_vector_type(8)));
typedef __bf16  bf16x4  __attribute__((ext_vector_type(4)));
typedef float   floatx4 __attribute__((ext_vector_type(4)));

// Bucket: 1 block, 256 threads (4 waves). Per-wave hist + scan + per-wave
// stable scatter; all atomics are intra-wave.
__global__ __launch_bounds__(256) void dl_bucket(const int* __restrict__ act,
                                                 int* __restrict__ counts,
                                                 int* __restrict__ offsets,
                                                 int* __restrict__ perm) {
    __shared__ int s_hist[4][NA];
    __shared__ int s_cur[4][NA];
    const int t = threadIdx.x;
    const int w = t >> 6;
    ((int*)s_hist)[t] = 0;
    __syncthreads();
    int myact[8];
#pragma unroll
    for (int i = 0; i < 8; ++i) {
        myact[i] = act[t + i * 256];
        atomicAdd(&s_hist[w][myact[i]], 1);
    }
    __syncthreads();
    if (t < NA) {                       // lanes 0..63 of wave 0
        const int h0 = s_hist[0][t], h1 = s_hist[1][t];
        const int h2 = s_hist[2][t], h3 = s_hist[3][t];
        const int tot = h0 + h1 + h2 + h3;
        int incl = tot;
#pragma unroll
        for (int d = 1; d < 64; d <<= 1) {
            int up = __shfl_up(incl, d, 64);
            if (t >= d) incl += up;
        }
        const int excl = incl - tot;
        counts[t]  = tot;
        offsets[t] = excl;
        s_cur[0][t] = excl;
        s_cur[1][t] = excl + h0;
        s_cur[2][t] = excl + h0 + h1;
        s_cur[3][t] = excl + h0 + h1 + h2;
    }
    __syncthreads();
#pragma unroll
    for (int i = 0; i < 8; ++i) {
        int pos = atomicAdd(&s_cur[w][myact[i]], 1);
        perm[pos] = t + i * 256;
    }
}

// Grouped GEMM. grid = (64 actions, 8 col-tiles), block = 256 (4 waves).
// Wave w owns cols [colbase + 16w, +16) x all m-chunks. Per K-chunk:
// coalesced fp32 loads -> regs (prefetched one chunk ahead, T14) ->
// cvt bf16 -> XOR-swizzled single LDS buffer -> ds_read_b128 fragments.
__global__ __launch_bounds__(256, 4) void dl_gemm(
        const float* __restrict__ x,
        const float* __restrict__ weight,
        const float* __restrict__ bias,
        const int*   __restrict__ counts,
        const int*   __restrict__ offsets,
        const int*   __restrict__ perm,
        float*       __restrict__ out)
{
    const int a   = blockIdx.x;          // action-major: the 8 tiles of one
    const int cnt = counts[a];           // action land on the same XCD
    if (cnt == 0) return;
    const int base = offsets[a];

    const int tid  = threadIdx.x;
    const int wave = tid >> 6;
    const int lane = tid & 63;
    const int l16  = lane & 15;
    const int kgrp = lane >> 4;
    const int colbase = blockIdx.y * BN;
    const int ncol    = colbase + wave * 16 + l16;

    // staging coords: 32 lanes per row, float4 each -> 512B contiguous/row
    const int srow = tid >> 5;           // 0..7 (stride 8)
    const int skk  = (tid & 31) << 2;    // float index 0..124

    const float* wtile  = weight + ((size_t)a * DD + colbase) * DD;
    const float  bias_v = bias[(size_t)a * DD + ncol];

    __shared__ __align__(16) __bf16 Ws[BN][BK];   // 16 KB (single buffer)
    __shared__ __align__(16) __bf16 Xs[64][BK];   // 16 KB
    __shared__ int s_perm[64];

    const int swzl = (l16 & 7) << 3;     // read swizzle (bf16 idx ^= (row&7)<<3)

    for (int m0 = 0; m0 < cnt; m0 += 64) {
        __syncthreads();                 // epilogue readers of s_perm done
        if (tid < 64) {
            int m = m0 + tid;
            s_perm[tid] = (m < cnt) ? perm[base + m] : 0;
        }
        __syncthreads();
        const int rem    = min(cnt - m0, 64);
        const int nchunk = (rem + 15) >> 4;

        floatx4 wreg[8], xreg[8];
        // prefetch chunk 0 into registers
#pragma unroll
        for (int i = 0; i < 8; ++i)
            wreg[i] = *(const floatx4*)(wtile + (size_t)(srow + i * 8) * DD + skk);
#pragma unroll
        for (int i = 0; i < 8; ++i) {
            const int r = srow + i * 8;
            if (r < rem)
                xreg[i] = *(const floatx4*)(x + (size_t)s_perm[r] * DD + skk);
        }

        floatx4 acc[4] = {{0,0,0,0},{0,0,0,0},{0,0,0,0},{0,0,0,0}};

        for (int kc = 0; kc < NKC; ++kc) {
            __syncthreads();             // all reads of previous chunk done
            // write prefetched regs -> LDS (cvt fp32->bf16, swizzled)
#pragma unroll
            for (int i = 0; i < 8; ++i) {
                const int r  = srow + i * 8;
                const int cc = skk ^ ((r & 7) << 3);
                bf16x4 wv;
#pragma unroll
                for (int j = 0; j < 4; ++j) wv[j] = (__bf16)wreg[i][j];
                *(bf16x4*)&Ws[r][cc] = wv;
            }
#pragma unroll
            for (int i = 0; i < 8; ++i) {
                const int r = srow + i * 8;
                if (r < rem) {
                    const int cc = skk ^ ((r & 7) << 3);
                    bf16x4 xv;
#pragma unroll
                    for (int j = 0; j < 4; ++j) xv[j] = (__bf16)xreg[i][j];
                    *(bf16x4*)&Xs[r][cc] = xv;
                }
            }
            // T14: issue next chunk's global loads now; they fly during
            // the barrier + compute below.
            if (kc + 1 < NKC) {
                const int ko = (kc + 1) * BK;
#pragma unroll
                for (int i = 0; i < 8; ++i)
                    wreg[i] = *(const floatx4*)(wtile + (size_t)(srow + i * 8) * DD + ko + skk);
#pragma unroll
                for (int i = 0; i < 8; ++i) {
                    const int r = srow + i * 8;
                    if (r < rem)
                        xreg[i] = *(const floatx4*)(x + (size_t)s_perm[r] * DD + ko + skk);
                }
            }
            __syncthreads();             // LDS writes visible
            // compute chunk kc
#pragma unroll
            for (int ks = 0; ks < BK / 32; ++ks) {
                const int kb = (ks * 32 + kgrp * 8) ^ swzl;
                const bf16x8 bfrag = *(const bf16x8*)&Ws[wave * 16 + l16][kb];
#pragma unroll
                for (int mc = 0; mc < 4; ++mc) {
                    if (mc < nchunk) {
                        const bf16x8 afrag = *(const bf16x8*)&Xs[mc * 16 + l16][kb];
                        acc[mc] = __builtin_amdgcn_mfma_f32_16x16x32_bf16(
                                      afrag, bfrag, acc[mc], 0, 0, 0);
                    }
                }
            }
        }

        // Epilogue: C/D layout col = lane&15 (-> ncol), row = kgrp*4 + r.
#pragma unroll
        for (int mc = 0; mc < 4; ++mc) {
            if (mc < nchunk) {
#pragma unroll
                for (int r = 0; r < 4; ++r) {
                    const int mloc = mc * 16 + kgrp * 4 + r;
                    if (mloc < rem)
                        out[(size_t)s_perm[mloc] * DD + ncol] = acc[mc][r] + bias_v;
                }
            }
        }
    }
}

extern "C" void kernel_launch(void* const* d_in, const int* in_sizes, int n_in,
                              void* d_out, int out_size, void* d_ws, size_t ws_size,
                              hipStream_t stream) {
    const float* x      = (const float*)d_in[0];
    const int*   act    = (const int*)  d_in[1];
    const float* weight = (const float*)d_in[2];
    const float* bias   = (const float*)d_in[3];
    float*       out    = (float*)d_out;

    int* counts  = (int*)d_ws;          // [64]
    int* offsets = counts + NA;         // [64]
    int* perm    = offsets + NA;        // [2048]

    dl_bucket<<<1, 256, 0, stream>>>(act, counts, offsets, perm);
    dl_gemm<<<dim3(NA, DD / BN), 256, 0, stream>>>(x, weight, bias,
                                                   counts, offsets, perm, out);
}

// Round 6
// 23.678 us; speedup vs baseline: 2.1626x; 2.1626x over previous
//
#include <hip/hip_runtime.h>

// DiscreteLinear: z[b,i] = sum_j weight[a[b],i,j] * x[b,j] + bias[a[b],i]
// B=2048, A=64, D=512.
// R5: single fused kernel.
//  - W has ZERO reuse -> no LDS staging for W; each lane loads its own
//    fragment rows direct from global (contiguous 32B/lane/kc, every 64B
//    line fully consumed across the kc loop). Barrier-free K-loop,
//    unroll 8 -> ~16 W loads in flight per wave (real MLP, no spill:
//    nothing is held across a barrier).
//  - x HAS reuse (8 blocks/action x all kc) -> staged in LDS ONCE per
//    block as swizzled bf16 (R4's per-chunk restage + barriers gone).
//  - bucketing folded into each block via ballot-compaction over act[]
//    (8KB/block, L2-hot) -> no separate kernel, no launch serialization.

#define NA 64
#define DD 512
#define NB 2048
#define BN 64           // output cols per block

typedef __bf16  bf16x8  __attribute__((ext_vector_type(8)));
typedef __bf16  bf16x4  __attribute__((ext_vector_type(4)));
typedef float   floatx4 __attribute__((ext_vector_type(4)));

static __device__ inline bf16x8 cvt8(floatx4 lo, floatx4 hi) {
    bf16x8 r;
    r[0] = (__bf16)lo[0]; r[1] = (__bf16)lo[1];
    r[2] = (__bf16)lo[2]; r[3] = (__bf16)lo[3];
    r[4] = (__bf16)hi[0]; r[5] = (__bf16)hi[1];
    r[6] = (__bf16)hi[2]; r[7] = (__bf16)hi[3];
    return r;
}

__global__ __launch_bounds__(256) void dl_fused(
        const float* __restrict__ x,
        const int*   __restrict__ act,
        const float* __restrict__ weight,
        const float* __restrict__ bias,
        float*       __restrict__ out)
{
    const int a    = blockIdx.x;         // the 8 tiles of one action share
    const int tid  = threadIdx.x;        // blockIdx.x%64 -> same XCD -> x L2-hits
    const int wave = tid >> 6;
    const int lane = tid & 63;
    const int l16  = lane & 15;
    const int kgrp = lane >> 4;
    const int colbase = blockIdx.y * BN;
    const int ncol    = colbase + wave * 16 + l16;

    __shared__ int s_perm[NB];                    // 8 KB
    __shared__ int s_wcnt[4];
    __shared__ __align__(16) __bf16 Xs[64][DD];   // 64 KB

    // ---- per-block bucket: ballot-compact indices with act[i]==a ----
    const int ibase = wave * (NB / 4);
    int wcnt = 0;
#pragma unroll
    for (int it = 0; it < NB / 4 / 64; ++it) {
        unsigned long long m = __ballot(act[ibase + it * 64 + lane] == a);
        wcnt += (int)__popcll(m);
    }
    if (lane == 0) s_wcnt[wave] = wcnt;
    __syncthreads();
    const int c0 = s_wcnt[0], c1 = s_wcnt[1], c2 = s_wcnt[2], c3 = s_wcnt[3];
    const int cnt = c0 + c1 + c2 + c3;
    if (cnt == 0) return;
    int off = (wave > 0 ? c0 : 0) + (wave > 1 ? c1 : 0) + (wave > 2 ? c2 : 0);
#pragma unroll
    for (int it = 0; it < NB / 4 / 64; ++it) {
        const int i = ibase + it * 64 + lane;
        const int av = act[i];                     // L1-hot re-read
        unsigned long long m = __ballot(av == a);
        if (av == a) {
            int pos = off + (int)__popcll(m & ((1ull << lane) - 1ull));
            s_perm[pos] = i;
        }
        off += (int)__popcll(m);
    }
    // s_perm made visible by the barrier at the top of the m0 loop.

    const int srow = tid >> 5;           // staging: 8 rows per pass
    const int skk  = (tid & 31) << 2;    // 32 lanes x float4 per row
    const float  bias_v = bias[(size_t)a * DD + ncol];
    const float* wrow   = weight + ((size_t)a * DD + ncol) * DD + kgrp * 8;
    const int swzl = (l16 & 7) << 3;     // fragment-read swizzle

    for (int m0 = 0; m0 < cnt; m0 += 64) {
        __syncthreads();                 // s_perm ready / prior Xs reads done
        const int rem    = min(cnt - m0, 64);
        const int nchunk = (rem + 15) >> 4;

        // ---- stage x rows [m0, m0+rem) into swizzled bf16 LDS (once) ----
#pragma unroll
        for (int i = 0; i < 8; ++i) {
            const int r = srow + i * 8;
            if (r < rem) {
                const float* xr = x + (size_t)s_perm[m0 + r] * DD;
                const int rs = (r & 7) << 3;
#pragma unroll
                for (int j = 0; j < 4; ++j) {
                    const int f0 = skk + j * 128;
                    floatx4 v = *(const floatx4*)(xr + f0);
                    bf16x4 bv;
#pragma unroll
                    for (int q = 0; q < 4; ++q) bv[q] = (__bf16)v[q];
                    *(bf16x4*)&Xs[r][f0 ^ rs] = bv;
                }
            }
        }
        __syncthreads();

        // ---- barrier-free K loop: W direct from global, x from LDS ----
        floatx4 acc[4] = {{0,0,0,0},{0,0,0,0},{0,0,0,0},{0,0,0,0}};
#pragma unroll 8
        for (int kc = 0; kc < DD / 32; ++kc) {
            const floatx4 w0 = *(const floatx4*)(wrow + kc * 32);
            const floatx4 w1 = *(const floatx4*)(wrow + kc * 32 + 4);
            const bf16x8 bfrag = cvt8(w0, w1);
            const int kb = (kc * 32 + kgrp * 8) ^ swzl;
#pragma unroll
            for (int mc = 0; mc < 4; ++mc) {
                if (mc < nchunk) {
                    const bf16x8 afrag = *(const bf16x8*)&Xs[mc * 16 + l16][kb];
                    acc[mc] = __builtin_amdgcn_mfma_f32_16x16x32_bf16(
                                  afrag, bfrag, acc[mc], 0, 0, 0);
                }
            }
        }

        // ---- epilogue: C/D layout col = lane&15 (-> ncol), row = kgrp*4+r ----
#pragma unroll
        for (int mc = 0; mc < 4; ++mc) {
            if (mc < nchunk) {
#pragma unroll
                for (int r = 0; r < 4; ++r) {
                    const int mloc = mc * 16 + kgrp * 4 + r;
                    if (mloc < rem)
                        out[(size_t)s_perm[m0 + mloc] * DD + ncol] =
                            acc[mc][r] + bias_v;
                }
            }
        }
    }
}

extern "C" void kernel_launch(void* const* d_in, const int* in_sizes, int n_in,
                              void* d_out, int out_size, void* d_ws, size_t ws_size,
                              hipStream_t stream) {
    const float* x      = (const float*)d_in[0];
    const int*   act    = (const int*)  d_in[1];
    const float* weight = (const float*)d_in[2];
    const float* bias   = (const float*)d_in[3];
    float*       out    = (float*)d_out;

    dl_fused<<<dim3(NA, DD / BN), 256, 0, stream>>>(x, act, weight, bias, out);
}